// Round 9
// baseline (167.172 us; speedup 1.0000x reference)
//
#include <hip/hip_runtime.h>
#include <math.h>

#define B_ 2
#define H_ 96
#define W_ 96
#define L_ (H_*W_)        // 9216
#define BL_ (B_*L_)       // 18432
#define DM_ 128
#define DI_ 256
#define DS_ 16
#define DR_ 8
#define C_ 576            // chunks per sequence
#define CL_ (L_/C_)       // 16 steps per chunk
#define G_ 24             // chunk groups per sequence
#define GC_ (C_/G_)       // 24 chunks per group

typedef __attribute__((ext_vector_type(8))) short short8;   // 8 bf16 in 4 VGPRs
typedef __attribute__((ext_vector_type(4))) float f32x4;    // MFMA accumulator

static __device__ __forceinline__ unsigned short f2bf(float f) {
  unsigned int u = __float_as_uint(f);
  unsigned int r = (u + 0x7fffu + ((u >> 16) & 1u)) >> 16;  // RNE
  return (unsigned short)r;
}
static __device__ __forceinline__ float bf2f(unsigned short u) {
  return __uint_as_float(((unsigned int)u) << 16);
}

// ---------------- Weight prep: packed bf16 fragment panels ----------------
__global__ __launch_bounds__(256) void k_wprep(const float* __restrict__ xpw,
                                               const float* __restrict__ dtw,
                                               const float* __restrict__ ipw,
                                               const float* __restrict__ opw,
                                               unsigned short* __restrict__ wallp,
                                               unsigned short* __restrict__ w2p,
                                               unsigned short* __restrict__ wop) {
  int bid = blockIdx.x, tid = threadIdx.x;
  if (bid < 288) {                       // Wall: 288 x 256 (K=256, 8 ks, 18 tiles)
    int n = bid, k = tid;
    float v;
    if (n < 256) {
      float s = 0.f;
#pragma unroll
      for (int r = 0; r < DR_; r++) s += xpw[r * DI_ + k] * dtw[n * DR_ + r];
      v = s;
    } else {
      v = xpw[(n - 248) * DI_ + k];      // B rows (8..23) and C rows (24..39)
    }
    int t = n >> 4, col = n & 15, ks = k >> 5, kk = k & 31;
    int lane = (kk >> 3) * 16 + col, i = kk & 7;
    wallp[(((ks * 18 + t) * 64 + lane) << 3) + i] = f2bf(v);
  } else if (bid < 544) {                // in_proj: 512 x 128 (K=128, 4 ks, 32 tiles)
    int n = (bid - 288) * 2 + (tid >> 7), k = tid & 127;
    int t = n >> 4, col = n & 15, ks = k >> 5, kk = k & 31;
    int lane = (kk >> 3) * 16 + col, i = kk & 7;
    w2p[(((ks * 32 + t) * 64 + lane) << 3) + i] = f2bf(ipw[n * DM_ + k]);
  } else {                               // out_proj: 128 x 256 (K=256, 8 ks, 8 tiles)
    int n = bid - 544, k = tid;
    int t = n >> 4, col = n & 15, ks = k >> 5, kk = k & 31;
    int lane = (kk >> 3) * 16 + col, i = kk & 7;
    wop[(((ks * 8 + t) * 64 + lane) << 3) + i] = f2bf(opw[n * DI_ + k]);
  }
}

// ---------------- x -> bf16 ----------------
__global__ __launch_bounds__(256) void k_xbf(const float* __restrict__ x,
                                             unsigned short* __restrict__ xbf) {
  int i = (blockIdx.x * 256 + threadIdx.x) * 8;
  float4 f0 = *(const float4*)(x + i);
  float4 f1 = *(const float4*)(x + i + 4);
  short8 o;
  o[0]=(short)f2bf(f0.x); o[1]=(short)f2bf(f0.y); o[2]=(short)f2bf(f0.z); o[3]=(short)f2bf(f0.w);
  o[4]=(short)f2bf(f1.x); o[5]=(short)f2bf(f1.y); o[6]=(short)f2bf(f1.z); o[7]=(short)f2bf(f1.w);
  *(short8*)(xbf + i) = o;
}

// ---------------- in_proj MFMA: (BL,128)x(128,512), col-split x4 ----------------
__global__ __launch_bounds__(256) void k_in_mfma(const unsigned short* __restrict__ xbf,
                                                 const unsigned short* __restrict__ w2p,
                                                 float* __restrict__ xi_raw,
                                                 unsigned short* __restrict__ zb) {
  int wid = threadIdx.x >> 6, lane = threadIdx.x & 63;
  int m0 = blockIdx.x * 64 + wid * 16;
  int t0 = blockIdx.y * 8;
  int row = m0 + (lane & 15);
  int col = lane & 15, r4 = (lane >> 4) * 4;
  f32x4 acc[8];
#pragma unroll
  for (int j = 0; j < 8; j++) acc[j] = (f32x4){0.f, 0.f, 0.f, 0.f};
#pragma unroll
  for (int ks = 0; ks < 4; ks++) {
    short8 a = *(const short8*)(xbf + (size_t)row * DM_ + ks * 32 + (lane >> 4) * 8);
#pragma unroll
    for (int j = 0; j < 8; j++) {
      short8 b = *(const short8*)(w2p + (((ks * 32 + t0 + j) * 64 + lane) << 3));
      acc[j] = __builtin_amdgcn_mfma_f32_16x16x32_bf16(a, b, acc[j], 0, 0, 0);
    }
  }
#pragma unroll
  for (int j = 0; j < 8; j++) {
    int tg = t0 + j;
    if (tg < 16) {
#pragma unroll
      for (int q = 0; q < 4; q++)
        xi_raw[(size_t)(m0 + r4 + q) * DI_ + tg * 16 + col] = acc[j][q];
    } else {
#pragma unroll
      for (int q = 0; q < 4; q++)
        zb[(size_t)(m0 + r4 + q) * DI_ + (tg - 16) * 16 + col] = f2bf(acc[j][q]);
    }
  }
}

// ---------------- depthwise 3x3 conv + bias + SiLU, 16-wide tiles, sliding window ----------------
__global__ __launch_bounds__(256) void k_conv(const float* __restrict__ xi_raw,
                                              const float* __restrict__ cw,
                                              const float* __restrict__ cb,
                                              float* __restrict__ xs,
                                              unsigned short* __restrict__ xs_bf) {
  int wt = blockIdx.x;        // 0..5
  int h  = blockIdx.y;        // 0..95
  int b  = blockIdx.z;        // 0..1
  int d  = threadIdx.x;       // channel
  int w0 = wt * 16;
  float wgt[9];
#pragma unroll
  for (int k = 0; k < 9; k++) wgt[k] = cw[d * 9 + k];
  float bias = cb[d];

  float v[3][18];
#pragma unroll
  for (int r = 0; r < 3; r++) {
    int hh = h - 1 + r;
    bool rok = (hh >= 0) & (hh < H_);
    const float* rowp = xi_raw + ((size_t)(b * H_ + hh) * W_) * DI_ + d;
#pragma unroll
    for (int j = 0; j < 18; j++) {
      int ww = w0 - 1 + j;
      bool ok = rok & (ww >= 0) & (ww < W_);
      v[r][j] = ok ? rowp[(size_t)ww * DI_] : 0.f;   // block-uniform predicate
    }
  }
#pragma unroll
  for (int j = 0; j < 16; j++) {
    float acc = bias;
#pragma unroll
    for (int r = 0; r < 3; r++)
#pragma unroll
      for (int q = 0; q < 3; q++)
        acc = fmaf(v[r][j + q], wgt[r * 3 + q], acc);
    float sg = 1.0f / (1.0f + __expf(-acc));
    float o = acc * sg;
    size_t bl = (size_t)(b * H_ + h) * W_ + w0 + j;
    xs[bl * DI_ + d] = o;
    xs_bf[bl * DI_ + d] = f2bf(o);
  }
}

// ---------------- x-side MFMA: (BL,256)x(256,288), col-split x3 ----------------
__global__ __launch_bounds__(256) void k_xmfma(const unsigned short* __restrict__ xs_bf,
                                               const unsigned short* __restrict__ wallp,
                                               const float* __restrict__ dtb,
                                               float* __restrict__ delta,
                                               float* __restrict__ Bsb,
                                               float* __restrict__ Csb) {
  int wid = threadIdx.x >> 6, lane = threadIdx.x & 63;
  int m0 = blockIdx.x * 64 + wid * 16;
  int t0 = blockIdx.y * 6;
  int row = m0 + (lane & 15);
  int col = lane & 15, r4 = (lane >> 4) * 4;
  f32x4 acc[6];
#pragma unroll
  for (int j = 0; j < 6; j++) acc[j] = (f32x4){0.f, 0.f, 0.f, 0.f};
#pragma unroll
  for (int ks = 0; ks < 8; ks++) {
    short8 a = *(const short8*)(xs_bf + (size_t)row * DI_ + ks * 32 + (lane >> 4) * 8);
#pragma unroll
    for (int j = 0; j < 6; j++) {
      short8 b = *(const short8*)(wallp + (((ks * 18 + t0 + j) * 64 + lane) << 3));
      acc[j] = __builtin_amdgcn_mfma_f32_16x16x32_bf16(a, b, acc[j], 0, 0, 0);
    }
  }
#pragma unroll
  for (int j = 0; j < 6; j++) {
    int t = t0 + j;
    if (t < 16) {
      float bias = dtb[t * 16 + col];
#pragma unroll
      for (int q = 0; q < 4; q++) {
        float v = acc[j][q] + bias;
        float sp = (v > 20.f) ? v : log1pf(__expf(v));
        delta[(size_t)(m0 + r4 + q) * DI_ + t * 16 + col] = sp;
      }
    } else if (t == 16) {
#pragma unroll
      for (int q = 0; q < 4; q++)
        Bsb[(size_t)(m0 + r4 + q) * DS_ + col] = acc[j][q];
    } else {
#pragma unroll
      for (int q = 0; q < 4; q++)
        Csb[(size_t)(m0 + r4 + q) * DS_ + col] = acc[j][q];
    }
  }
}

// ---------------- Scan pass 1: per-chunk local state (thread = d, all loads batched) ----------------
__global__ __launch_bounds__(256) void k_scan1(const float* __restrict__ delta,
                                               const float* __restrict__ xs,
                                               const float* __restrict__ Bsb,
                                               const float* __restrict__ A_logs,
                                               float* __restrict__ S_buf,
                                               float* __restrict__ sumD_buf) {
  int c = blockIdx.x, b = blockIdx.y;
  int d = threadIdx.x;
  float a2[DS_];
#pragma unroll
  for (int n = 0; n < DS_; n++)
    a2[n] = -__expf(A_logs[d * DS_ + n]) * 1.44269504f;
  size_t base = (size_t)b * L_ + (size_t)c * CL_;
  float dvA[CL_], xvA[CL_];
#pragma unroll
  for (int s = 0; s < CL_; s++) {
    dvA[s] = delta[(base + s) * DI_ + d];
    xvA[s] = xs[(base + s) * DI_ + d];
  }
  float h[DS_];
#pragma unroll
  for (int n = 0; n < DS_; n++) h[n] = 0.f;
  float sum = 0.f;
#pragma unroll
  for (int s = 0; s < CL_; s++) {
    const float4* Brow = (const float4*)(Bsb + (base + s) * DS_);  // wave-uniform
    float4 b0 = Brow[0], b1 = Brow[1], b2 = Brow[2], b3 = Brow[3];
    float Bv[DS_] = {b0.x,b0.y,b0.z,b0.w, b1.x,b1.y,b1.z,b1.w,
                     b2.x,b2.y,b2.z,b2.w, b3.x,b3.y,b3.z,b3.w};
    float dv = dvA[s];
    float dvx = dv * xvA[s];
    sum += dv;
#pragma unroll
    for (int n = 0; n < DS_; n++)
      h[n] = fmaf(exp2f(dv * a2[n]), h[n], dvx * Bv[n]);
  }
  size_t o = ((size_t)(b * C_ + c) * DI_ + d) * DS_;
#pragma unroll
  for (int q = 0; q < 4; q++)
    *(float4*)(S_buf + o + 4 * q) = (float4){h[4*q], h[4*q+1], h[4*q+2], h[4*q+3]};
  sumD_buf[(size_t)(b * C_ + c) * DI_ + d] = sum;
}

// ---------------- Scan pass 2a: group-local chunk prefix ----------------
__global__ __launch_bounds__(256) void k_scan2a(const float* __restrict__ S_buf,
                                                float* __restrict__ sumD_csd,
                                                const float* __restrict__ A_logs,
                                                float* __restrict__ hin_loc,
                                                float* __restrict__ HgS,
                                                float* __restrict__ gsd) {
  int t = blockIdx.x * 256 + threadIdx.x;   // 0 .. B*G*DI*DS-1
  int n = t & 15;
  int d = (t >> 4) & 255;
  int gg = t >> 12;            // b*G_ + g  (0..B*G-1)
  int b = gg / G_;
  int g = gg - b * G_;
  float a2 = -__expf(A_logs[d * DS_ + n]) * 1.44269504f;
  float h = 0.f, csd = 0.f;
  int c0 = b * C_ + g * GC_;
#pragma unroll
  for (int j = 0; j < GC_; j++) {
    size_t o  = ((size_t)(c0 + j) * DI_ + d) * DS_ + n;
    size_t od = (size_t)(c0 + j) * DI_ + d;
    float S  = S_buf[o];
    float sd = sumD_csd[od];
    hin_loc[o] = h;
    if (n == 0) sumD_csd[od] = csd;
    csd += sd;
    h = fmaf(exp2f(a2 * sd), h, S);
  }
  size_t og = ((size_t)(b * G_ + g) * DI_ + d) * DS_ + n;
  HgS[og] = h;
  if (n == 0) gsd[(size_t)(b * G_ + g) * DI_ + d] = csd;
}

// ---------------- Scan pass 2b: combine group summaries ----------------
__global__ __launch_bounds__(256) void k_scan2b(float* __restrict__ HgS_Hpre,
                                                const float* __restrict__ gsd,
                                                const float* __restrict__ A_logs) {
  int t = blockIdx.x * 256 + threadIdx.x;   // 0 .. 8191
  int b = t >> 12;
  int d = (t >> 4) & 255;
  int n = t & 15;
  float a2 = -__expf(A_logs[d * DS_ + n]) * 1.44269504f;
  float h = 0.f;
#pragma unroll
  for (int g = 0; g < G_; g++) {
    size_t o = ((size_t)(b * G_ + g) * DI_ + d) * DS_ + n;
    float Hg = HgS_Hpre[o];
    float sd = gsd[(size_t)(b * G_ + g) * DI_ + d];
    HgS_Hpre[o] = h;
    h = fmaf(exp2f(a2 * sd), h, Hg);
  }
}

// ---------------- Scan pass 3 + fused LayerNorm + SiLU(z) gate -> g bf16 ----------------
// g is stored in the first 512 bytes of each 1KB xs row (block overwrites only rows
// it already consumed into registers -> race-free).
__global__ __launch_bounds__(256) void k_scan3(const float* __restrict__ delta,
                                               const float* __restrict__ xs,
                                               const float* __restrict__ Bsb,
                                               const float* __restrict__ Csb,
                                               const float* __restrict__ A_logs,
                                               const float* __restrict__ Ds,
                                               const float* __restrict__ hin_loc,
                                               const float* __restrict__ Hpre,
                                               const float* __restrict__ csd,
                                               const unsigned short* __restrict__ zb,
                                               const float* __restrict__ lng,
                                               const float* __restrict__ lnb,
                                               unsigned short* __restrict__ g) {
  int c = blockIdx.x, b = blockIdx.y;
  int d = threadIdx.x;
  int grp = c / GC_;
  __shared__ float ysm[CL_][DI_];
  __shared__ float smu[CL_], srs[CL_];
  float a2[DS_];
#pragma unroll
  for (int n = 0; n < DS_; n++)
    a2[n] = -__expf(A_logs[d * DS_ + n]) * 1.44269504f;
  float Dv = Ds[d];
  size_t base = (size_t)b * L_ + (size_t)c * CL_;
  float dvA[CL_], xvA[CL_];
#pragma unroll
  for (int s = 0; s < CL_; s++) {
    dvA[s] = delta[(base + s) * DI_ + d];
    xvA[s] = xs[(base + s) * DI_ + d];
  }
  // seed: h = hin_loc + exp2(a2*csd) * Hpre[grp]
  float h[DS_];
  {
    size_t ho = ((size_t)(b * C_ + c) * DI_ + d) * DS_;
    size_t go = ((size_t)(b * G_ + grp) * DI_ + d) * DS_;
    float cs = csd[(size_t)(b * C_ + c) * DI_ + d];
#pragma unroll
    for (int q = 0; q < 4; q++) {
      float4 tl = *(const float4*)(hin_loc + ho + 4 * q);
      float4 tp = *(const float4*)(Hpre + go + 4 * q);
      h[4*q+0] = fmaf(exp2f(cs * a2[4*q+0]), tp.x, tl.x);
      h[4*q+1] = fmaf(exp2f(cs * a2[4*q+1]), tp.y, tl.y);
      h[4*q+2] = fmaf(exp2f(cs * a2[4*q+2]), tp.z, tl.z);
      h[4*q+3] = fmaf(exp2f(cs * a2[4*q+3]), tp.w, tl.w);
    }
  }
#pragma unroll
  for (int s = 0; s < CL_; s++) {
    const float4* Brow = (const float4*)(Bsb + (base + s) * DS_);
    const float4* Crow = (const float4*)(Csb + (base + s) * DS_);
    float4 b0 = Brow[0], b1 = Brow[1], b2 = Brow[2], b3 = Brow[3];
    float4 c0 = Crow[0], c1 = Crow[1], c2 = Crow[2], c3 = Crow[3];
    float Bv[DS_] = {b0.x,b0.y,b0.z,b0.w, b1.x,b1.y,b1.z,b1.w,
                     b2.x,b2.y,b2.z,b2.w, b3.x,b3.y,b3.z,b3.w};
    float Cv[DS_] = {c0.x,c0.y,c0.z,c0.w, c1.x,c1.y,c1.z,c1.w,
                     c2.x,c2.y,c2.z,c2.w, c3.x,c3.y,c3.z,c3.w};
    float dv = dvA[s], xv = xvA[s];
    float dvx = dv * xv;
    float y0 = Dv * xv, y1 = 0.f, y2 = 0.f, y3 = 0.f;
#pragma unroll
    for (int k = 0; k < 4; k++) {
      int n0 = k, n1_ = 4 + k, n2 = 8 + k, n3 = 12 + k;
      h[n0] = fmaf(exp2f(dv * a2[n0]), h[n0], dvx * Bv[n0]);
      y0 = fmaf(h[n0], Cv[n0], y0);
      h[n1_] = fmaf(exp2f(dv * a2[n1_]), h[n1_], dvx * Bv[n1_]);
      y1 = fmaf(h[n1_], Cv[n1_], y1);
      h[n2] = fmaf(exp2f(dv * a2[n2]), h[n2], dvx * Bv[n2]);
      y2 = fmaf(h[n2], Cv[n2], y2);
      h[n3] = fmaf(exp2f(dv * a2[n3]), h[n3], dvx * Bv[n3]);
      y3 = fmaf(h[n3], Cv[n3], y3);
    }
    ysm[s][d] = (y0 + y1) + (y2 + y3);
  }
  __syncthreads();
  {
    int wid = d >> 6, lane = d & 63;
#pragma unroll
    for (int s4 = 0; s4 < CL_ / 4; s4++) {
      int s = wid * (CL_ / 4) + s4;
      float p0 = ysm[s][lane], p1 = ysm[s][lane + 64];
      float p2 = ysm[s][lane + 128], p3 = ysm[s][lane + 192];
      float s1 = (p0 + p1) + (p2 + p3);
      float s2 = (p0*p0 + p1*p1) + (p2*p2 + p3*p3);
#pragma unroll
      for (int off = 32; off >= 1; off >>= 1) {
        s1 += __shfl_xor(s1, off);
        s2 += __shfl_xor(s2, off);
      }
      if (lane == 0) {
        float mu = s1 / DI_;
        smu[s] = mu;
        srs[s] = rsqrtf(s2 / DI_ - mu * mu + 1e-5f);
      }
    }
  }
  __syncthreads();
  float lg = lng[d], lb = lnb[d];
#pragma unroll
  for (int s = 0; s < CL_; s++) {
    float v = (ysm[s][d] - smu[s]) * srs[s] * lg + lb;
    float zz = bf2f(zb[(base + s) * DI_ + d]);
    float sg = zz / (1.f + __expf(-zz));
    g[(base + s) * 512 + d] = f2bf(v * sg);
  }
}

// ---------------- out stage 2 MFMA: (BL,256)x(256,128), col-split x2 ----------------
// g row stride = 512 ushorts (first half of each 1KB xs row)
__global__ __launch_bounds__(256) void k_out2(const unsigned short* __restrict__ gbf,
                                              const unsigned short* __restrict__ wop,
                                              float* __restrict__ out) {
  int wid = threadIdx.x >> 6, lane = threadIdx.x & 63;
  int m0 = blockIdx.x * 64 + wid * 16;
  int t0 = blockIdx.y * 4;
  int row = m0 + (lane & 15);
  int col = lane & 15, r4 = (lane >> 4) * 4;
  f32x4 acc[4];
#pragma unroll
  for (int j = 0; j < 4; j++) acc[j] = (f32x4){0.f, 0.f, 0.f, 0.f};
#pragma unroll
  for (int ks = 0; ks < 8; ks++) {
    short8 a = *(const short8*)(gbf + (size_t)row * 512 + ks * 32 + (lane >> 4) * 8);
#pragma unroll
    for (int j = 0; j < 4; j++) {
      short8 b = *(const short8*)(wop + (((ks * 8 + t0 + j) * 64 + lane) << 3));
      acc[j] = __builtin_amdgcn_mfma_f32_16x16x32_bf16(a, b, acc[j], 0, 0, 0);
    }
  }
#pragma unroll
  for (int j = 0; j < 4; j++)
#pragma unroll
    for (int q = 0; q < 4; q++)
      out[(size_t)(m0 + r4 + q) * DM_ + (t0 + j) * 16 + col] = acc[j][q];
}

extern "C" void kernel_launch(void* const* d_in, const int* in_sizes, int n_in,
                              void* d_out, int out_size, void* d_ws, size_t ws_size,
                              hipStream_t stream) {
  const float* x         = (const float*)d_in[0];
  const float* in_proj_w = (const float*)d_in[1];
  const float* conv_w    = (const float*)d_in[2];
  const float* conv_b    = (const float*)d_in[3];
  const float* x_proj_w  = (const float*)d_in[4];
  const float* dt_w      = (const float*)d_in[5];
  const float* dt_b      = (const float*)d_in[6];
  const float* A_logs    = (const float*)d_in[7];
  const float* Ds        = (const float*)d_in[8];
  const float* ln_g      = (const float*)d_in[9];
  const float* ln_b      = (const float*)d_in[10];
  const float* out_proj_w= (const float*)d_in[11];
  float* out = (float*)d_out;

  float* ws = (float*)d_ws;
  size_t n1 = (size_t)BL_ * DI_;
  // slot 0: xi_raw -> S_buf (B*C*DI*DS = n1 floats exactly at C_=576)
  float* xi_raw = ws;
  // slot 1: z bf16 + xs bf16
  unsigned short* z_bf  = (unsigned short*)(ws + n1);
  unsigned short* xs_bf = z_bf + n1;
  // slot 2: xs fp32; g bf16 lives in first 512B of each 1KB row (scan3 fusion)
  float* xs     = ws + 2 * n1;
  unsigned short* g_bf = (unsigned short*)xs;
  // slot 3: delta fp32
  float* delta  = ws + 3 * n1;
  float* Bsb    = ws + 4 * n1;
  float* Csb    = Bsb + (size_t)BL_ * DS_;
  float* hin_loc= Csb + (size_t)BL_ * DS_;                       // n1 floats (18.9 MB)
  float* sumD   = hin_loc + (size_t)B_ * C_ * DI_ * DS_;
  float* HgS    = sumD + (size_t)B_ * C_ * DI_;
  float* gsd    = HgS + (size_t)B_ * G_ * DI_ * DS_;
  unsigned short* wallp = (unsigned short*)(gsd + (size_t)B_ * G_ * DI_);
  unsigned short* w2p   = wallp + 288 * DI_;
  unsigned short* wop   = w2p + 512 * DM_;
  unsigned short* x_bf  = (unsigned short*)hin_loc;  // scratch; dead before scan2a writes
  float* S_buf  = xi_raw;

  k_wprep<<<672, 256, 0, stream>>>(x_proj_w, dt_w, in_proj_w, out_proj_w, wallp, w2p, wop);
  k_xbf<<<(BL_ * DM_) / 2048, 256, 0, stream>>>(x, x_bf);
  k_in_mfma<<<dim3(BL_ / 64, 4), 256, 0, stream>>>(x_bf, w2p, xi_raw, z_bf);
  k_conv<<<dim3(W_ / 16, H_, B_), 256, 0, stream>>>(xi_raw, conv_w, conv_b, xs, xs_bf);
  k_xmfma<<<dim3(BL_ / 64, 3), 256, 0, stream>>>(xs_bf, wallp, dt_b, delta, Bsb, Csb);
  k_scan1<<<dim3(C_, B_), 256, 0, stream>>>(delta, xs, Bsb, A_logs, S_buf, sumD);
  k_scan2a<<<(B_ * G_ * DI_ * DS_) / 256, 256, 0, stream>>>(S_buf, sumD, A_logs, hin_loc, HgS, gsd);
  k_scan2b<<<(B_ * DI_ * DS_) / 256, 256, 0, stream>>>(HgS, gsd, A_logs);
  k_scan3<<<dim3(C_, B_), 256, 0, stream>>>(delta, xs, Bsb, Csb, A_logs, Ds, hin_loc, HgS, sumD,
                                            z_bf, ln_g, ln_b, g_bf);
  k_out2<<<dim3(BL_ / 64, 2), 256, 0, stream>>>(g_bf, wop, out);
}

// Round 10
// 142.749 us; speedup vs baseline: 1.1711x; 1.1711x over previous
//
#include <hip/hip_runtime.h>
#include <math.h>

#define B_ 2
#define H_ 96
#define W_ 96
#define L_ (H_*W_)        // 9216
#define BL_ (B_*L_)       // 18432
#define DM_ 128
#define DI_ 256
#define DS_ 16
#define DR_ 8
#define C_ 384            // chunks per sequence
#define CL_ (L_/C_)       // 24 steps per chunk
#define G_ 16             // chunk groups per sequence
#define GC_ (C_/G_)       // 24 chunks per group

typedef __attribute__((ext_vector_type(8))) short short8;   // 8 bf16 in 4 VGPRs
typedef __attribute__((ext_vector_type(4))) float f32x4;    // MFMA accumulator

static __device__ __forceinline__ unsigned short f2bf(float f) {
  unsigned int u = __float_as_uint(f);
  unsigned int r = (u + 0x7fffu + ((u >> 16) & 1u)) >> 16;  // RNE
  return (unsigned short)r;
}
static __device__ __forceinline__ float bf2f(unsigned short u) {
  return __uint_as_float(((unsigned int)u) << 16);
}

// ---------------- Weight prep (packed bf16 fragment panels) + x->bf16 ----------------
__global__ __launch_bounds__(256) void k_wprep(const float* __restrict__ xpw,
                                               const float* __restrict__ dtw,
                                               const float* __restrict__ ipw,
                                               const float* __restrict__ opw,
                                               const float* __restrict__ x,
                                               unsigned short* __restrict__ wallp,
                                               unsigned short* __restrict__ w2p,
                                               unsigned short* __restrict__ wop,
                                               unsigned short* __restrict__ xbf) {
  int bid = blockIdx.x, tid = threadIdx.x;
  if (bid < 288) {                       // Wall: 288 x 256 (K=256, 8 ks, 18 tiles)
    int n = bid, k = tid;
    float v;
    if (n < 256) {
      float s = 0.f;
#pragma unroll
      for (int r = 0; r < DR_; r++) s += xpw[r * DI_ + k] * dtw[n * DR_ + r];
      v = s;
    } else {
      v = xpw[(n - 248) * DI_ + k];      // B rows (8..23) and C rows (24..39)
    }
    int t = n >> 4, col = n & 15, ks = k >> 5, kk = k & 31;
    int lane = (kk >> 3) * 16 + col, i = kk & 7;
    wallp[(((ks * 18 + t) * 64 + lane) << 3) + i] = f2bf(v);
  } else if (bid < 544) {                // in_proj: 512 x 128 (K=128, 4 ks, 32 tiles)
    int n = (bid - 288) * 2 + (tid >> 7), k = tid & 127;
    int t = n >> 4, col = n & 15, ks = k >> 5, kk = k & 31;
    int lane = (kk >> 3) * 16 + col, i = kk & 7;
    w2p[(((ks * 32 + t) * 64 + lane) << 3) + i] = f2bf(ipw[n * DM_ + k]);
  } else if (bid < 672) {                // out_proj: 128 x 256 (K=256, 8 ks, 8 tiles)
    int n = bid - 544, k = tid;
    int t = n >> 4, col = n & 15, ks = k >> 5, kk = k & 31;
    int lane = (kk >> 3) * 16 + col, i = kk & 7;
    wop[(((ks * 8 + t) * 64 + lane) << 3) + i] = f2bf(opw[n * DI_ + k]);
  } else {                               // x -> bf16
    int i = ((bid - 672) * 256 + tid) * 8;
    float4 f0 = *(const float4*)(x + i);
    float4 f1 = *(const float4*)(x + i + 4);
    short8 o;
    o[0]=(short)f2bf(f0.x); o[1]=(short)f2bf(f0.y); o[2]=(short)f2bf(f0.z); o[3]=(short)f2bf(f0.w);
    o[4]=(short)f2bf(f1.x); o[5]=(short)f2bf(f1.y); o[6]=(short)f2bf(f1.z); o[7]=(short)f2bf(f1.w);
    *(short8*)(xbf + i) = o;
  }
}

// ---------------- in_proj MFMA: (BL,128)x(128,512), col-split x4 ----------------
__global__ __launch_bounds__(256) void k_in_mfma(const unsigned short* __restrict__ xbf,
                                                 const unsigned short* __restrict__ w2p,
                                                 float* __restrict__ xi_raw,
                                                 unsigned short* __restrict__ zb) {
  int wid = threadIdx.x >> 6, lane = threadIdx.x & 63;
  int m0 = blockIdx.x * 64 + wid * 16;
  int t0 = blockIdx.y * 8;
  int row = m0 + (lane & 15);
  int col = lane & 15, r4 = (lane >> 4) * 4;
  f32x4 acc[8];
#pragma unroll
  for (int j = 0; j < 8; j++) acc[j] = (f32x4){0.f, 0.f, 0.f, 0.f};
#pragma unroll
  for (int ks = 0; ks < 4; ks++) {
    short8 a = *(const short8*)(xbf + (size_t)row * DM_ + ks * 32 + (lane >> 4) * 8);
#pragma unroll
    for (int j = 0; j < 8; j++) {
      short8 b = *(const short8*)(w2p + (((ks * 32 + t0 + j) * 64 + lane) << 3));
      acc[j] = __builtin_amdgcn_mfma_f32_16x16x32_bf16(a, b, acc[j], 0, 0, 0);
    }
  }
#pragma unroll
  for (int j = 0; j < 8; j++) {
    int tg = t0 + j;
    if (tg < 16) {
#pragma unroll
      for (int q = 0; q < 4; q++)
        xi_raw[(size_t)(m0 + r4 + q) * DI_ + tg * 16 + col] = acc[j][q];
    } else {
#pragma unroll
      for (int q = 0; q < 4; q++)
        zb[(size_t)(m0 + r4 + q) * DI_ + (tg - 16) * 16 + col] = f2bf(acc[j][q]);
    }
  }
}

// ---------------- depthwise 3x3 conv + bias + SiLU -> xs bf16 only ----------------
__global__ __launch_bounds__(256) void k_conv(const float* __restrict__ xi_raw,
                                              const float* __restrict__ cw,
                                              const float* __restrict__ cb,
                                              unsigned short* __restrict__ xs_bf) {
  int wt = blockIdx.x;        // 0..5
  int h  = blockIdx.y;        // 0..95
  int b  = blockIdx.z;        // 0..1
  int d  = threadIdx.x;       // channel
  int w0 = wt * 16;
  float wgt[9];
#pragma unroll
  for (int k = 0; k < 9; k++) wgt[k] = cw[d * 9 + k];
  float bias = cb[d];

  float v[3][18];
#pragma unroll
  for (int r = 0; r < 3; r++) {
    int hh = h - 1 + r;
    bool rok = (hh >= 0) & (hh < H_);
    const float* rowp = xi_raw + ((size_t)(b * H_ + hh) * W_) * DI_ + d;
#pragma unroll
    for (int j = 0; j < 18; j++) {
      int ww = w0 - 1 + j;
      bool ok = rok & (ww >= 0) & (ww < W_);
      v[r][j] = ok ? rowp[(size_t)ww * DI_] : 0.f;   // block-uniform predicate
    }
  }
#pragma unroll
  for (int j = 0; j < 16; j++) {
    float acc = bias;
#pragma unroll
    for (int r = 0; r < 3; r++)
#pragma unroll
      for (int q = 0; q < 3; q++)
        acc = fmaf(v[r][j + q], wgt[r * 3 + q], acc);
    float sg = 1.0f / (1.0f + __expf(-acc));
    float o = acc * sg;
    size_t bl = (size_t)(b * H_ + h) * W_ + w0 + j;
    xs_bf[bl * DI_ + d] = f2bf(o);
  }
}

// ---------------- x-side MFMA: (BL,256)x(256,288), col-split x3 ----------------
__global__ __launch_bounds__(256) void k_xmfma(const unsigned short* __restrict__ xs_bf,
                                               const unsigned short* __restrict__ wallp,
                                               const float* __restrict__ dtb,
                                               float* __restrict__ delta,
                                               float* __restrict__ Bsb,
                                               float* __restrict__ Csb) {
  int wid = threadIdx.x >> 6, lane = threadIdx.x & 63;
  int m0 = blockIdx.x * 64 + wid * 16;
  int t0 = blockIdx.y * 6;
  int row = m0 + (lane & 15);
  int col = lane & 15, r4 = (lane >> 4) * 4;
  f32x4 acc[6];
#pragma unroll
  for (int j = 0; j < 6; j++) acc[j] = (f32x4){0.f, 0.f, 0.f, 0.f};
#pragma unroll
  for (int ks = 0; ks < 8; ks++) {
    short8 a = *(const short8*)(xs_bf + (size_t)row * DI_ + ks * 32 + (lane >> 4) * 8);
#pragma unroll
    for (int j = 0; j < 6; j++) {
      short8 b = *(const short8*)(wallp + (((ks * 18 + t0 + j) * 64 + lane) << 3));
      acc[j] = __builtin_amdgcn_mfma_f32_16x16x32_bf16(a, b, acc[j], 0, 0, 0);
    }
  }
#pragma unroll
  for (int j = 0; j < 6; j++) {
    int t = t0 + j;
    if (t < 16) {
      float bias = dtb[t * 16 + col];
#pragma unroll
      for (int q = 0; q < 4; q++) {
        float v = acc[j][q] + bias;
        float sp = (v > 20.f) ? v : log1pf(__expf(v));
        delta[(size_t)(m0 + r4 + q) * DI_ + t * 16 + col] = sp;
      }
    } else if (t == 16) {
#pragma unroll
      for (int q = 0; q < 4; q++)
        Bsb[(size_t)(m0 + r4 + q) * DS_ + col] = acc[j][q];
    } else {
#pragma unroll
      for (int q = 0; q < 4; q++)
        Csb[(size_t)(m0 + r4 + q) * DS_ + col] = acc[j][q];
    }
  }
}

// ---------------- Scan pass 1: register-batched chunk scan, B staged in LDS ----------------
__global__ __launch_bounds__(256, 3) void k_scan1(const float* __restrict__ delta,
                                                  const unsigned short* __restrict__ xs_bf,
                                                  const float* __restrict__ Bsb,
                                                  const float* __restrict__ A_logs,
                                                  float* __restrict__ S_buf,
                                                  float* __restrict__ sumD_buf) {
  int c = blockIdx.x, b = blockIdx.y;
  int d = threadIdx.x;
  __shared__ float sB[CL_][DS_];
  size_t base = (size_t)b * L_ + (size_t)c * CL_;
  for (int i = d; i < CL_ * DS_; i += 256)
    sB[i >> 4][i & 15] = Bsb[base * DS_ + i];
  float a2[DS_];
#pragma unroll
  for (int n = 0; n < DS_; n++)
    a2[n] = -__expf(A_logs[d * DS_ + n]) * 1.44269504f;
  float dvA[CL_], xvA[CL_];
#pragma unroll
  for (int s = 0; s < CL_; s++) {
    dvA[s] = delta[(base + s) * DI_ + d];
    xvA[s] = bf2f(xs_bf[(base + s) * DI_ + d]);
  }
  __syncthreads();
  float h[DS_];
#pragma unroll
  for (int n = 0; n < DS_; n++) h[n] = 0.f;
  float sum = 0.f;
#pragma unroll
  for (int s = 0; s < CL_; s++) {
    float4 b0 = *(const float4*)&sB[s][0];
    float4 b1 = *(const float4*)&sB[s][4];
    float4 b2 = *(const float4*)&sB[s][8];
    float4 b3 = *(const float4*)&sB[s][12];
    float Bv[DS_] = {b0.x,b0.y,b0.z,b0.w, b1.x,b1.y,b1.z,b1.w,
                     b2.x,b2.y,b2.z,b2.w, b3.x,b3.y,b3.z,b3.w};
    float dv = dvA[s];
    float dvx = dv * xvA[s];
    sum += dv;
#pragma unroll
    for (int n = 0; n < DS_; n++)
      h[n] = fmaf(exp2f(dv * a2[n]), h[n], dvx * Bv[n]);
  }
  size_t o = ((size_t)(b * C_ + c) * DI_ + d) * DS_;
#pragma unroll
  for (int q = 0; q < 4; q++)
    *(float4*)(S_buf + o + 4 * q) = (float4){h[4*q], h[4*q+1], h[4*q+2], h[4*q+3]};
  sumD_buf[(size_t)(b * C_ + c) * DI_ + d] = sum;
}

// ---------------- Scan pass 2a: group-local chunk prefix (prefetched) ----------------
__global__ __launch_bounds__(256) void k_scan2a(const float* __restrict__ S_buf,
                                                float* __restrict__ sumD_csd,
                                                const float* __restrict__ A_logs,
                                                float* __restrict__ hin_loc,
                                                float* __restrict__ HgS,
                                                float* __restrict__ gsd) {
  int t = blockIdx.x * 256 + threadIdx.x;   // 0 .. B*G*DI*DS-1
  int b = t >> 16;
  int g = (t >> 12) & 15;
  int d = (t >> 4) & 255;
  int n = t & 15;
  float a2 = -__expf(A_logs[d * DS_ + n]) * 1.44269504f;
  float h = 0.f, csd = 0.f;
  int c0 = b * C_ + g * GC_;
  const size_t stride = (size_t)DI_ * DS_;
  size_t o  = ((size_t)c0 * DI_ + d) * DS_ + n;
  size_t od = (size_t)c0 * DI_ + d;
  float S  = S_buf[o];
  float sd = sumD_csd[od];
#pragma unroll
  for (int j = 0; j < GC_; j++) {
    float Sn = 0.f, sdn = 0.f;
    if (j + 1 < GC_) {
      Sn  = S_buf[o + stride];
      sdn = sumD_csd[od + DI_];
    }
    hin_loc[o] = h;
    if (n == 0) sumD_csd[od] = csd;
    csd += sd;
    h = fmaf(exp2f(a2 * sd), h, S);
    S = Sn; sd = sdn;
    o += stride; od += DI_;
  }
  size_t og = ((size_t)(b * G_ + g) * DI_ + d) * DS_ + n;
  HgS[og] = h;
  if (n == 0) gsd[(size_t)(b * G_ + g) * DI_ + d] = csd;
}

// ---------------- Scan pass 2b: combine group summaries ----------------
__global__ __launch_bounds__(256) void k_scan2b(float* __restrict__ HgS_Hpre,
                                                const float* __restrict__ gsd,
                                                const float* __restrict__ A_logs) {
  int t = blockIdx.x * 256 + threadIdx.x;   // 0 .. 8191
  int b = t >> 12;
  int d = (t >> 4) & 255;
  int n = t & 15;
  float a2 = -__expf(A_logs[d * DS_ + n]) * 1.44269504f;
  float h = 0.f;
#pragma unroll
  for (int g = 0; g < G_; g++) {
    size_t o = ((size_t)(b * G_ + g) * DI_ + d) * DS_ + n;
    float Hg = HgS_Hpre[o];
    float sd = gsd[(size_t)(b * G_ + g) * DI_ + d];
    HgS_Hpre[o] = h;
    h = fmaf(exp2f(a2 * sd), h, Hg);
  }
}

// ---------------- Scan pass 3 + fused LayerNorm + SiLU(z) gate -> g bf16 ----------------
__global__ __launch_bounds__(256, 3) void k_scan3(const float* __restrict__ delta,
                                                   const unsigned short* __restrict__ xs_bf,
                                                   const float* __restrict__ Bsb,
                                                   const float* __restrict__ Csb,
                                                   const float* __restrict__ A_logs,
                                                   const float* __restrict__ Ds,
                                                   const float* __restrict__ hin_loc,
                                                   const float* __restrict__ Hpre,
                                                   const float* __restrict__ csd,
                                                   const unsigned short* __restrict__ zb,
                                                   const float* __restrict__ lng,
                                                   const float* __restrict__ lnb,
                                                   unsigned short* __restrict__ g) {
  int c = blockIdx.x, b = blockIdx.y;
  int d = threadIdx.x;
  int grp = c / GC_;
  __shared__ float ysm[CL_][DI_];
  __shared__ float sBC[2][CL_][DS_];
  __shared__ float smu[CL_], srs[CL_];
  size_t base = (size_t)b * L_ + (size_t)c * CL_;
  for (int i = d; i < CL_ * DS_; i += 256) {
    sBC[0][i >> 4][i & 15] = Bsb[base * DS_ + i];
    sBC[1][i >> 4][i & 15] = Csb[base * DS_ + i];
  }
  float a2[DS_];
#pragma unroll
  for (int n = 0; n < DS_; n++)
    a2[n] = -__expf(A_logs[d * DS_ + n]) * 1.44269504f;
  float Dv = Ds[d];
  float dvA[CL_], xvA[CL_];
#pragma unroll
  for (int s = 0; s < CL_; s++) {
    dvA[s] = delta[(base + s) * DI_ + d];
    xvA[s] = bf2f(xs_bf[(base + s) * DI_ + d]);
  }
  // seed: h = hin_loc + exp2(a2*csd) * Hpre[grp]
  float h[DS_];
  {
    size_t ho = ((size_t)(b * C_ + c) * DI_ + d) * DS_;
    size_t go = ((size_t)(b * G_ + grp) * DI_ + d) * DS_;
    float cs = csd[(size_t)(b * C_ + c) * DI_ + d];
#pragma unroll
    for (int q = 0; q < 4; q++) {
      float4 tl = *(const float4*)(hin_loc + ho + 4 * q);
      float4 tp = *(const float4*)(Hpre + go + 4 * q);
      h[4*q+0] = fmaf(exp2f(cs * a2[4*q+0]), tp.x, tl.x);
      h[4*q+1] = fmaf(exp2f(cs * a2[4*q+1]), tp.y, tl.y);
      h[4*q+2] = fmaf(exp2f(cs * a2[4*q+2]), tp.z, tl.z);
      h[4*q+3] = fmaf(exp2f(cs * a2[4*q+3]), tp.w, tl.w);
    }
  }
  __syncthreads();
#pragma unroll
  for (int s = 0; s < CL_; s++) {
    float4 b0 = *(const float4*)&sBC[0][s][0];
    float4 b1 = *(const float4*)&sBC[0][s][4];
    float4 b2 = *(const float4*)&sBC[0][s][8];
    float4 b3 = *(const float4*)&sBC[0][s][12];
    float4 c0 = *(const float4*)&sBC[1][s][0];
    float4 c1 = *(const float4*)&sBC[1][s][4];
    float4 c2 = *(const float4*)&sBC[1][s][8];
    float4 c3 = *(const float4*)&sBC[1][s][12];
    float Bv[DS_] = {b0.x,b0.y,b0.z,b0.w, b1.x,b1.y,b1.z,b1.w,
                     b2.x,b2.y,b2.z,b2.w, b3.x,b3.y,b3.z,b3.w};
    float Cv[DS_] = {c0.x,c0.y,c0.z,c0.w, c1.x,c1.y,c1.z,c1.w,
                     c2.x,c2.y,c2.z,c2.w, c3.x,c3.y,c3.z,c3.w};
    float dv = dvA[s], xv = xvA[s];
    float dvx = dv * xv;
    float y0 = Dv * xv, y1 = 0.f, y2 = 0.f, y3 = 0.f;
#pragma unroll
    for (int k = 0; k < 4; k++) {
      int n0 = k, n1_ = 4 + k, n2 = 8 + k, n3 = 12 + k;
      h[n0] = fmaf(exp2f(dv * a2[n0]), h[n0], dvx * Bv[n0]);
      y0 = fmaf(h[n0], Cv[n0], y0);
      h[n1_] = fmaf(exp2f(dv * a2[n1_]), h[n1_], dvx * Bv[n1_]);
      y1 = fmaf(h[n1_], Cv[n1_], y1);
      h[n2] = fmaf(exp2f(dv * a2[n2]), h[n2], dvx * Bv[n2]);
      y2 = fmaf(h[n2], Cv[n2], y2);
      h[n3] = fmaf(exp2f(dv * a2[n3]), h[n3], dvx * Bv[n3]);
      y3 = fmaf(h[n3], Cv[n3], y3);
    }
    ysm[s][d] = (y0 + y1) + (y2 + y3);
  }
  __syncthreads();
  {
    int wid = d >> 6, lane = d & 63;
#pragma unroll
    for (int s6 = 0; s6 < CL_ / 4; s6++) {
      int s = wid * (CL_ / 4) + s6;
      float p0 = ysm[s][lane], p1 = ysm[s][lane + 64];
      float p2 = ysm[s][lane + 128], p3 = ysm[s][lane + 192];
      float s1 = (p0 + p1) + (p2 + p3);
      float s2 = (p0*p0 + p1*p1) + (p2*p2 + p3*p3);
#pragma unroll
      for (int off = 32; off >= 1; off >>= 1) {
        s1 += __shfl_xor(s1, off);
        s2 += __shfl_xor(s2, off);
      }
      if (lane == 0) {
        float mu = s1 / DI_;
        smu[s] = mu;
        srs[s] = rsqrtf(s2 / DI_ - mu * mu + 1e-5f);
      }
    }
  }
  __syncthreads();
  float lg = lng[d], lb = lnb[d];
#pragma unroll
  for (int s = 0; s < CL_; s++) {
    float v = (ysm[s][d] - smu[s]) * srs[s] * lg + lb;
    float zz = bf2f(zb[(base + s) * DI_ + d]);
    float sg = zz / (1.f + __expf(-zz));
    g[(base + s) * DI_ + d] = f2bf(v * sg);
  }
}

// ---------------- out stage 2 MFMA: (BL,256)x(256,128), col-split x2 ----------------
__global__ __launch_bounds__(256) void k_out2(const unsigned short* __restrict__ gbf,
                                              const unsigned short* __restrict__ wop,
                                              float* __restrict__ out) {
  int wid = threadIdx.x >> 6, lane = threadIdx.x & 63;
  int m0 = blockIdx.x * 64 + wid * 16;
  int t0 = blockIdx.y * 4;
  int row = m0 + (lane & 15);
  int col = lane & 15, r4 = (lane >> 4) * 4;
  f32x4 acc[4];
#pragma unroll
  for (int j = 0; j < 4; j++) acc[j] = (f32x4){0.f, 0.f, 0.f, 0.f};
#pragma unroll
  for (int ks = 0; ks < 8; ks++) {
    short8 a = *(const short8*)(gbf + (size_t)row * DI_ + ks * 32 + (lane >> 4) * 8);
#pragma unroll
    for (int j = 0; j < 4; j++) {
      short8 b = *(const short8*)(wop + (((ks * 8 + t0 + j) * 64 + lane) << 3));
      acc[j] = __builtin_amdgcn_mfma_f32_16x16x32_bf16(a, b, acc[j], 0, 0, 0);
    }
  }
#pragma unroll
  for (int j = 0; j < 4; j++)
#pragma unroll
    for (int q = 0; q < 4; q++)
      out[(size_t)(m0 + r4 + q) * DM_ + (t0 + j) * 16 + col] = acc[j][q];
}

extern "C" void kernel_launch(void* const* d_in, const int* in_sizes, int n_in,
                              void* d_out, int out_size, void* d_ws, size_t ws_size,
                              hipStream_t stream) {
  const float* x         = (const float*)d_in[0];
  const float* in_proj_w = (const float*)d_in[1];
  const float* conv_w    = (const float*)d_in[2];
  const float* conv_b    = (const float*)d_in[3];
  const float* x_proj_w  = (const float*)d_in[4];
  const float* dt_w      = (const float*)d_in[5];
  const float* dt_b      = (const float*)d_in[6];
  const float* A_logs    = (const float*)d_in[7];
  const float* Ds        = (const float*)d_in[8];
  const float* ln_g      = (const float*)d_in[9];
  const float* ln_b      = (const float*)d_in[10];
  const float* out_proj_w= (const float*)d_in[11];
  float* out = (float*)d_out;

  float* ws = (float*)d_ws;
  size_t n1 = (size_t)BL_ * DI_;
  // slot 0: xi_raw -> S_buf
  float* xi_raw = ws;
  // slot 1: z bf16 + xs bf16
  unsigned short* z_bf  = (unsigned short*)(ws + n1);
  unsigned short* xs_bf = z_bf + n1;
  // slot 2: g bf16 (dense, BL x 256)
  unsigned short* g_bf  = (unsigned short*)(ws + 2 * n1);
  // slot 3: delta fp32
  float* delta  = ws + 3 * n1;
  float* Bsb    = ws + 4 * n1;
  float* Csb    = Bsb + (size_t)BL_ * DS_;
  float* hin_loc= Csb + (size_t)BL_ * DS_;                       // B*C*DI*DS = 12.6 MB
  float* sumD   = hin_loc + (size_t)B_ * C_ * DI_ * DS_;
  float* HgS    = sumD + (size_t)B_ * C_ * DI_;
  float* gsd    = HgS + (size_t)B_ * G_ * DI_ * DS_;
  unsigned short* wallp = (unsigned short*)(gsd + (size_t)B_ * G_ * DI_);
  unsigned short* w2p   = wallp + 288 * DI_;
  unsigned short* wop   = w2p + 512 * DM_;
  unsigned short* x_bf  = (unsigned short*)hin_loc;  // scratch; dead before scan2a writes
  float* S_buf  = xi_raw;

  k_wprep<<<672 + (BL_ * DM_) / 2048, 256, 0, stream>>>(x_proj_w, dt_w, in_proj_w, out_proj_w, x,
                                                        wallp, w2p, wop, x_bf);
  k_in_mfma<<<dim3(BL_ / 64, 4), 256, 0, stream>>>(x_bf, w2p, xi_raw, z_bf);
  k_conv<<<dim3(W_ / 16, H_, B_), 256, 0, stream>>>(xi_raw, conv_w, conv_b, xs_bf);
  k_xmfma<<<dim3(BL_ / 64, 3), 256, 0, stream>>>(xs_bf, wallp, dt_b, delta, Bsb, Csb);
  k_scan1<<<dim3(C_, B_), 256, 0, stream>>>(delta, xs_bf, Bsb, A_logs, S_buf, sumD);
  k_scan2a<<<(B_ * G_ * DI_ * DS_) / 256, 256, 0, stream>>>(S_buf, sumD, A_logs, hin_loc, HgS, gsd);
  k_scan2b<<<(B_ * DI_ * DS_) / 256, 256, 0, stream>>>(HgS, gsd, A_logs);
  k_scan3<<<dim3(C_, B_), 256, 0, stream>>>(delta, xs_bf, Bsb, Csb, A_logs, Ds, hin_loc, HgS, sumD,
                                            z_bf, ln_g, ln_b, g_bf);
  k_out2<<<dim3(BL_ / 64, 2), 256, 0, stream>>>(g_bf, wop, out);
}